// Round 1
// baseline (57.092 us; speedup 1.0000x reference)
//
#include <hip/hip_runtime.h>

// YOLO-style loss, faithful to the (buggy) reference _xyxy: center = w/S for both x and y.
// loss = (5*(xy+wh) + obj + 0.5*noobj) / 1024, summed over 1024*80*80 cells.

#define S_INV (1.0f / 80.0f)

__global__ void zero_out_kernel(float* out) {
    out[0] = 0.0f;
}

__global__ __launch_bounds__(256) void yolo_loss_kernel(
    const float4* __restrict__ pred4,   // 5 float4 per 4-cell group (20 floats)
    const float4* __restrict__ targ4,   // 4 float4 per 4-cell group (16 floats)
    const int4*  __restrict__ mask4,    // 1 int4  per 4-cell group
    float* __restrict__ out,
    int ngroups)
{
    float acc = 0.0f;
    int tid = blockIdx.x * blockDim.x + threadIdx.x;
    int stride = gridDim.x * blockDim.x;

    for (int g = tid; g < ngroups; g += stride) {
        float p[20];
        float t[16];
        float4 v;
        v = pred4[5 * g + 0]; p[ 0] = v.x; p[ 1] = v.y; p[ 2] = v.z; p[ 3] = v.w;
        v = pred4[5 * g + 1]; p[ 4] = v.x; p[ 5] = v.y; p[ 6] = v.z; p[ 7] = v.w;
        v = pred4[5 * g + 2]; p[ 8] = v.x; p[ 9] = v.y; p[10] = v.z; p[11] = v.w;
        v = pred4[5 * g + 3]; p[12] = v.x; p[13] = v.y; p[14] = v.z; p[15] = v.w;
        v = pred4[5 * g + 4]; p[16] = v.x; p[17] = v.y; p[18] = v.z; p[19] = v.w;
        v = targ4[4 * g + 0]; t[ 0] = v.x; t[ 1] = v.y; t[ 2] = v.z; t[ 3] = v.w;
        v = targ4[4 * g + 1]; t[ 4] = v.x; t[ 5] = v.y; t[ 6] = v.z; t[ 7] = v.w;
        v = targ4[4 * g + 2]; t[ 8] = v.x; t[ 9] = v.y; t[10] = v.z; t[11] = v.w;
        v = targ4[4 * g + 3]; t[12] = v.x; t[13] = v.y; t[14] = v.z; t[15] = v.w;
        int4 mi = mask4[g];
        int mm[4] = { mi.x, mi.y, mi.z, mi.w };

        #pragma unroll
        for (int j = 0; j < 4; ++j) {
            float px = p[5 * j + 0], py = p[5 * j + 1], pw = p[5 * j + 2];
            float ph = p[5 * j + 3], pc = p[5 * j + 4];
            float tx = t[4 * j + 0], ty = t[4 * j + 1], tw = t[4 * j + 2], th = t[4 * j + 3];

            // _xyxy (faithful to reference bug: center is w/S for BOTH axes)
            float cp = pw * S_INV;
            float ct = tw * S_INV;
            float px1 = cp - 0.5f * pw, py1 = cp - 0.5f * ph;
            float px2 = cp + 0.5f * pw, py2 = cp + 0.5f * ph;
            float tx1 = ct - 0.5f * tw, ty1 = ct - 0.5f * th;
            float tx2 = ct + 0.5f * tw, ty2 = ct + 0.5f * th;

            float iw = fmaxf(fminf(px2, tx2) - fmaxf(px1, tx1), 0.0f);
            float ih = fmaxf(fminf(py2, ty2) - fmaxf(py1, ty1), 0.0f);
            float inter = iw * ih;
            float uni = pw * ph + tw * th - inter;
            float iou = inter / uni;

            float dx = px - tx, dy = py - ty;
            float sw = sqrtf(pw) - sqrtf(tw);
            float sh = sqrtf(ph) - sqrtf(th);
            float dobj = pc - iou;

            float obj_term = 5.0f * ((dx * dx + dy * dy) + (sw * sw + sh * sh)) + dobj * dobj;
            float noobj_term = 0.5f * pc * pc;
            acc += (mm[j] > 0) ? obj_term : noobj_term;
        }
    }

    // wave (64-lane) shuffle reduction
    #pragma unroll
    for (int off = 32; off > 0; off >>= 1)
        acc += __shfl_down(acc, off, 64);

    __shared__ float wsum[4];
    int lane = threadIdx.x & 63;
    int wid = threadIdx.x >> 6;
    if (lane == 0) wsum[wid] = acc;
    __syncthreads();

    if (threadIdx.x == 0) {
        float b = wsum[0] + wsum[1] + wsum[2] + wsum[3];
        atomicAdd(out, b * (1.0f / 1024.0f));
    }
}

extern "C" void kernel_launch(void* const* d_in, const int* in_sizes, int n_in,
                              void* d_out, int out_size, void* d_ws, size_t ws_size,
                              hipStream_t stream) {
    const float4* pred4 = (const float4*)d_in[0];   // [1024,80,80,5] f32
    const float4* targ4 = (const float4*)d_in[1];   // [1024,80,80,4] f32
    const int4*   mask4 = (const int4*)d_in[2];     // [1024,80,80]   i32
    float* out = (float*)d_out;

    int ncells = in_sizes[2];            // 1024*80*80 = 6,553,600
    int ngroups = ncells / 4;            // 1,638,400 (divisible)

    zero_out_kernel<<<1, 1, 0, stream>>>(out);

    const int block = 256;
    const int grid = 2048;               // ~8 blocks/CU worth of waves; grid-stride covers rest
    yolo_loss_kernel<<<grid, block, 0, stream>>>(pred4, targ4, mask4, out, ngroups);
}

// Round 2
// 56.296 us; speedup vs baseline: 1.0141x; 1.0141x over previous
//
#include <hip/hip_runtime.h>

// YOLO-style loss, faithful to the (buggy) reference _xyxy: center = w/S for both x and y.
// loss = (5*(xy+wh) + obj + 0.5*noobj) / 1024, summed over 1024*80*80 cells.
//
// R1: LDS-staged coalesced loads. R0's direct loads had 80B inter-lane stride
// (each vmem instr touched ~80 cache lines) -> issue-rate bound at 57us,
// VALUBusy 20%, HBM 17%. Stage pred/targ through LDS with unit-stride loads.

#define S_INV (1.0f / 80.0f)

__global__ void zero_out_kernel(float* out) {
    out[0] = 0.0f;
}

__global__ __launch_bounds__(256) void yolo_loss_kernel(
    const float4* __restrict__ pred4,   // 5 float4 per 4-cell group
    const float4* __restrict__ targ4,   // 4 float4 per 4-cell group
    const int4*  __restrict__ mask4,    // 1 int4  per 4-cell group
    float* __restrict__ out,
    int ngroups)
{
    // 256 groups per block-iteration, 1 group (4 cells) per thread.
    __shared__ float4 lp[5 * 256];      // pred: thread t owns lp[5t .. 5t+4]      (20 KB)
    __shared__ float4 lt[5 * 256];      // targ padded: logical j -> phys j+(j>>2) (20 KB)

    const int t = threadIdx.x;
    float acc = 0.0f;

    for (int base = blockIdx.x * 256; base < ngroups; base += gridDim.x * 256) {
        // ---- stage (coalesced, unit inter-lane stride) ----
        #pragma unroll
        for (int i = 0; i < 5; ++i)
            lp[i * 256 + t] = pred4[base * 5 + i * 256 + t];
        #pragma unroll
        for (int i = 0; i < 4; ++i) {
            int j = i * 256 + t;
            lt[j + (j >> 2)] = targ4[base * 4 + j];
        }
        int4 mi = mask4[base + t];
        int mm[4] = { mi.x, mi.y, mi.z, mi.w };
        __syncthreads();

        // ---- compute: thread t's 4 cells ----
        float p[20];
        float tv[16];
        #pragma unroll
        for (int i = 0; i < 5; ++i) {
            float4 v = lp[5 * t + i];
            p[4 * i + 0] = v.x; p[4 * i + 1] = v.y; p[4 * i + 2] = v.z; p[4 * i + 3] = v.w;
        }
        #pragma unroll
        for (int i = 0; i < 4; ++i) {
            float4 v = lt[5 * t + i];            // phys 5t+i == logical 4t+i
            tv[4 * i + 0] = v.x; tv[4 * i + 1] = v.y; tv[4 * i + 2] = v.z; tv[4 * i + 3] = v.w;
        }

        #pragma unroll
        for (int j = 0; j < 4; ++j) {
            float px = p[5 * j + 0], py = p[5 * j + 1], pw = p[5 * j + 2];
            float ph = p[5 * j + 3], pc = p[5 * j + 4];
            float tx = tv[4 * j + 0], ty = tv[4 * j + 1], tw = tv[4 * j + 2], th = tv[4 * j + 3];

            // _xyxy (faithful to reference bug: center is w/S for BOTH axes)
            float cp = pw * S_INV;
            float ct = tw * S_INV;
            float px1 = cp - 0.5f * pw, py1 = cp - 0.5f * ph;
            float px2 = cp + 0.5f * pw, py2 = cp + 0.5f * ph;
            float tx1 = ct - 0.5f * tw, ty1 = ct - 0.5f * th;
            float tx2 = ct + 0.5f * tw, ty2 = ct + 0.5f * th;

            float iw = fmaxf(fminf(px2, tx2) - fmaxf(px1, tx1), 0.0f);
            float ih = fmaxf(fminf(py2, ty2) - fmaxf(py1, ty1), 0.0f);
            float inter = iw * ih;
            float uni = pw * ph + tw * th - inter;
            float iou = inter / uni;

            float dx = px - tx, dy = py - ty;
            float sw = sqrtf(pw) - sqrtf(tw);
            float sh = sqrtf(ph) - sqrtf(th);
            float dobj = pc - iou;

            float obj_term = 5.0f * ((dx * dx + dy * dy) + (sw * sw + sh * sh)) + dobj * dobj;
            float noobj_term = 0.5f * pc * pc;
            acc += (mm[j] > 0) ? obj_term : noobj_term;
        }
        __syncthreads();   // protect LDS before next stage overwrites
    }

    // wave (64-lane) shuffle reduction
    #pragma unroll
    for (int off = 32; off > 0; off >>= 1)
        acc += __shfl_down(acc, off, 64);

    __shared__ float wsum[4];
    int lane = threadIdx.x & 63;
    int wid = threadIdx.x >> 6;
    if (lane == 0) wsum[wid] = acc;
    __syncthreads();

    if (threadIdx.x == 0) {
        float b = wsum[0] + wsum[1] + wsum[2] + wsum[3];
        atomicAdd(out, b * (1.0f / 1024.0f));
    }
}

extern "C" void kernel_launch(void* const* d_in, const int* in_sizes, int n_in,
                              void* d_out, int out_size, void* d_ws, size_t ws_size,
                              hipStream_t stream) {
    const float4* pred4 = (const float4*)d_in[0];   // [1024,80,80,5] f32
    const float4* targ4 = (const float4*)d_in[1];   // [1024,80,80,4] f32
    const int4*   mask4 = (const int4*)d_in[2];     // [1024,80,80]   i32
    float* out = (float*)d_out;

    int ncells = in_sizes[2];            // 1024*80*80 = 6,553,600
    int ngroups = ncells / 4;            // 1,638,400 (divisible by 256)

    zero_out_kernel<<<1, 1, 0, stream>>>(out);

    const int block = 256;
    const int grid = 2048;               // grid-stride; 6400 block-iterations total
    yolo_loss_kernel<<<grid, block, 0, stream>>>(pred4, targ4, mask4, out, ngroups);
}

// Round 3
// 55.238 us; speedup vs baseline: 1.0336x; 1.0192x over previous
//
#include <hip/hip_runtime.h>

// YOLO-style loss, faithful to the (buggy) reference _xyxy: center = w/S for both x and y.
// loss = (5*(xy+wh) + obj + 0.5*noobj) / 1024, summed over 1024*80*80 cells.
//
// R2: software-pipelined direct loads. R0/R1 both ~57us with all pipes idle ->
// latency-bound hypothesis: each wave drained vmcnt to 0 before compute.
// Prefetch next group's 10 loads before computing current group (no LDS, no barriers).

#define S_INV (1.0f / 80.0f)

__global__ void zero_out_kernel(float* out) {
    out[0] = 0.0f;
}

struct Grp {
    float4 p0, p1, p2, p3, p4;   // 20 pred floats (4 cells x 5)
    float4 t0, t1, t2, t3;       // 16 targ floats (4 cells x 4)
    int4   m;                    // 4 mask ints
};

__device__ __forceinline__ void load_grp(Grp& g,
                                         const float4* __restrict__ pred4,
                                         const float4* __restrict__ targ4,
                                         const int4*  __restrict__ mask4,
                                         int idx)
{
    g.p0 = pred4[5 * idx + 0];
    g.p1 = pred4[5 * idx + 1];
    g.p2 = pred4[5 * idx + 2];
    g.p3 = pred4[5 * idx + 3];
    g.p4 = pred4[5 * idx + 4];
    g.t0 = targ4[4 * idx + 0];
    g.t1 = targ4[4 * idx + 1];
    g.t2 = targ4[4 * idx + 2];
    g.t3 = targ4[4 * idx + 3];
    g.m  = mask4[idx];
}

__device__ __forceinline__ float cell_loss(float px, float py, float pw, float ph, float pc,
                                           float tx, float ty, float tw, float th, int m)
{
    // _xyxy (faithful to reference bug: center is w/S for BOTH axes)
    float cp = pw * S_INV;
    float ct = tw * S_INV;
    float px1 = cp - 0.5f * pw, py1 = cp - 0.5f * ph;
    float px2 = cp + 0.5f * pw, py2 = cp + 0.5f * ph;
    float tx1 = ct - 0.5f * tw, ty1 = ct - 0.5f * th;
    float tx2 = ct + 0.5f * tw, ty2 = ct + 0.5f * th;

    float iw = fmaxf(fminf(px2, tx2) - fmaxf(px1, tx1), 0.0f);
    float ih = fmaxf(fminf(py2, ty2) - fmaxf(py1, ty1), 0.0f);
    float inter = iw * ih;
    float uni = pw * ph + tw * th - inter;
    float iou = inter / uni;

    float dx = px - tx, dy = py - ty;
    float sw = sqrtf(pw) - sqrtf(tw);
    float sh = sqrtf(ph) - sqrtf(th);
    float dobj = pc - iou;

    float obj_term = 5.0f * ((dx * dx + dy * dy) + (sw * sw + sh * sh)) + dobj * dobj;
    float noobj_term = 0.5f * pc * pc;
    return (m > 0) ? obj_term : noobj_term;
}

__device__ __forceinline__ float compute_grp(const Grp& g)
{
    float s = 0.0f;
    // cell 0: p0.xyzw + p1.x ; t0
    s += cell_loss(g.p0.x, g.p0.y, g.p0.z, g.p0.w, g.p1.x,
                   g.t0.x, g.t0.y, g.t0.z, g.t0.w, g.m.x);
    // cell 1: p1.yzw + p2.xy ; t1
    s += cell_loss(g.p1.y, g.p1.z, g.p1.w, g.p2.x, g.p2.y,
                   g.t1.x, g.t1.y, g.t1.z, g.t1.w, g.m.y);
    // cell 2: p2.zw + p3.xyz ; t2
    s += cell_loss(g.p2.z, g.p2.w, g.p3.x, g.p3.y, g.p3.z,
                   g.t2.x, g.t2.y, g.t2.z, g.t2.w, g.m.z);
    // cell 3: p3.w + p4.xyzw ; t3
    s += cell_loss(g.p3.w, g.p4.x, g.p4.y, g.p4.z, g.p4.w,
                   g.t3.x, g.t3.y, g.t3.z, g.t3.w, g.m.w);
    return s;
}

__global__ __launch_bounds__(256) void yolo_loss_kernel(
    const float4* __restrict__ pred4,
    const float4* __restrict__ targ4,
    const int4*  __restrict__ mask4,
    float* __restrict__ out,
    int ngroups)
{
    float acc = 0.0f;
    int tid = blockIdx.x * blockDim.x + threadIdx.x;
    int stride = gridDim.x * blockDim.x;

    int g = tid;
    Grp A, B;
    bool haveA = (g < ngroups);
    if (haveA) load_grp(A, pred4, targ4, mask4, g);

    // software pipeline: loads for g2 are in flight while computing A
    #pragma unroll 2
    for (int g2 = g + stride; g2 < ngroups; g2 += stride) {
        load_grp(B, pred4, targ4, mask4, g2);
        acc += compute_grp(A);
        A = B;
    }
    if (haveA) acc += compute_grp(A);

    // wave (64-lane) shuffle reduction
    #pragma unroll
    for (int off = 32; off > 0; off >>= 1)
        acc += __shfl_down(acc, off, 64);

    __shared__ float wsum[4];
    int lane = threadIdx.x & 63;
    int wid = threadIdx.x >> 6;
    if (lane == 0) wsum[wid] = acc;
    __syncthreads();

    if (threadIdx.x == 0) {
        float b = wsum[0] + wsum[1] + wsum[2] + wsum[3];
        atomicAdd(out, b * (1.0f / 1024.0f));
    }
}

extern "C" void kernel_launch(void* const* d_in, const int* in_sizes, int n_in,
                              void* d_out, int out_size, void* d_ws, size_t ws_size,
                              hipStream_t stream) {
    const float4* pred4 = (const float4*)d_in[0];   // [1024,80,80,5] f32
    const float4* targ4 = (const float4*)d_in[1];   // [1024,80,80,4] f32
    const int4*   mask4 = (const int4*)d_in[2];     // [1024,80,80]   i32
    float* out = (float*)d_out;

    int ncells = in_sizes[2];            // 1024*80*80 = 6,553,600
    int ngroups = ncells / 4;            // 1,638,400

    zero_out_kernel<<<1, 1, 0, stream>>>(out);

    const int block = 256;
    const int grid = 2048;
    yolo_loss_kernel<<<grid, block, 0, stream>>>(pred4, targ4, mask4, out, ngroups);
}